// Round 1
// baseline (1111.949 us; speedup 1.0000x reference)
//
#include <hip/hip_runtime.h>

#define N_NODES 100000
#define IN_C 128
#define HID 128
#define OUTC 64
#define NE 500000
#define NEP 100000

// ---------------- scatter: one 64-lane group per edge, 128 channels, 2/lane ----
template<bool ADD_DEG>
__global__ __launch_bounds__(256) void scatter_kernel(
    const float* __restrict__ feat,       // [N][128]
    const int* __restrict__ ei,           // [2][NE] (src row 0, dst row 1)
    float* __restrict__ agg,              // [N][128]
    float* __restrict__ deg) {            // [N]
    int g = blockIdx.x * 4 + (threadIdx.x >> 6);   // edge id
    if (g >= NE) return;
    int lane = threadIdx.x & 63;
    int src = ei[g];
    int dst = ei[NE + g];
    const float2 v = *reinterpret_cast<const float2*>(feat + (size_t)src * 128 + lane * 2);
    float* p = agg + (size_t)dst * 128 + lane * 2;
    unsafeAtomicAdd(p, v.x);
    unsafeAtomicAdd(p + 1, v.y);
    if (ADD_DEG && lane == 0) unsafeAtomicAdd(deg + dst, 1.0f);
}

// ---------------- layer 1: h = relu(mean@Wl + x@Wr + b), 128 outputs ----------
__global__ __launch_bounds__(128) void l1_kernel(
    const float* __restrict__ x, const float* __restrict__ agg,
    const float* __restrict__ deg,
    const float* __restrict__ Wl, const float* __restrict__ Wr,
    const float* __restrict__ b, float* __restrict__ h) {
    __shared__ float xs[8][128];
    __shared__ float ms[8][128];
    const int j = threadIdx.x;
    const int n0 = blockIdx.x * 8;
#pragma unroll
    for (int nb = 0; nb < 8; ++nb) {
        int n = n0 + nb;
        float inv = 1.0f / fmaxf(deg[n], 1.0f);
        xs[nb][j] = x[(size_t)n * 128 + j];
        ms[nb][j] = agg[(size_t)n * 128 + j] * inv;
    }
    __syncthreads();
    float acc[8];
#pragma unroll
    for (int nb = 0; nb < 8; ++nb) acc[nb] = 0.0f;
    for (int c = 0; c < 128; c += 4) {
        float wl0 = Wl[(c + 0) * 128 + j], wl1 = Wl[(c + 1) * 128 + j];
        float wl2 = Wl[(c + 2) * 128 + j], wl3 = Wl[(c + 3) * 128 + j];
        float wr0 = Wr[(c + 0) * 128 + j], wr1 = Wr[(c + 1) * 128 + j];
        float wr2 = Wr[(c + 2) * 128 + j], wr3 = Wr[(c + 3) * 128 + j];
#pragma unroll
        for (int nb = 0; nb < 8; ++nb) {
            float4 m4 = *reinterpret_cast<const float4*>(&ms[nb][c]);
            float4 x4 = *reinterpret_cast<const float4*>(&xs[nb][c]);
            acc[nb] += m4.x * wl0 + m4.y * wl1 + m4.z * wl2 + m4.w * wl3
                     + x4.x * wr0 + x4.y * wr1 + x4.z * wr2 + x4.w * wr3;
        }
    }
    float bj = b[j];
#pragma unroll
    for (int nb = 0; nb < 8; ++nb) {
        int n = n0 + nb;
        h[(size_t)n * 128 + j] = fmaxf(acc[nb] + bj, 0.0f);
    }
}

// ---------------- layer 2: z = mean@Wl + h@Wr + b, 64 outputs -----------------
__global__ __launch_bounds__(64) void l2_kernel(
    const float* __restrict__ h, const float* __restrict__ agg,
    const float* __restrict__ deg,
    const float* __restrict__ Wl, const float* __restrict__ Wr,
    const float* __restrict__ b, float* __restrict__ z) {
    __shared__ float hs[8][128];
    __shared__ float ms[8][128];
    const int j = threadIdx.x;  // 0..63
    const int n0 = blockIdx.x * 8;
#pragma unroll
    for (int nb = 0; nb < 8; ++nb) {
        int n = n0 + nb;
        float inv = 1.0f / fmaxf(deg[n], 1.0f);
        hs[nb][j]      = h[(size_t)n * 128 + j];
        hs[nb][j + 64] = h[(size_t)n * 128 + 64 + j];
        ms[nb][j]      = agg[(size_t)n * 128 + j] * inv;
        ms[nb][j + 64] = agg[(size_t)n * 128 + 64 + j] * inv;
    }
    __syncthreads();
    float acc[8];
#pragma unroll
    for (int nb = 0; nb < 8; ++nb) acc[nb] = 0.0f;
    for (int c = 0; c < 128; c += 4) {
        float wl0 = Wl[(c + 0) * 64 + j], wl1 = Wl[(c + 1) * 64 + j];
        float wl2 = Wl[(c + 2) * 64 + j], wl3 = Wl[(c + 3) * 64 + j];
        float wr0 = Wr[(c + 0) * 64 + j], wr1 = Wr[(c + 1) * 64 + j];
        float wr2 = Wr[(c + 2) * 64 + j], wr3 = Wr[(c + 3) * 64 + j];
#pragma unroll
        for (int nb = 0; nb < 8; ++nb) {
            float4 m4 = *reinterpret_cast<const float4*>(&ms[nb][c]);
            float4 h4 = *reinterpret_cast<const float4*>(&hs[nb][c]);
            acc[nb] += m4.x * wl0 + m4.y * wl1 + m4.z * wl2 + m4.w * wl3
                     + h4.x * wr0 + h4.y * wr1 + h4.z * wr2 + h4.w * wr3;
        }
    }
    float bj = b[j];
#pragma unroll
    for (int nb = 0; nb < 8; ++nb) {
        int n = n0 + nb;
        z[(size_t)n * 64 + j] = acc[nb] + bj;
    }
}

// ---------------- decode: 16 lanes per edge, dot over 64 dims ------------------
__global__ __launch_bounds__(256) void decode_kernel(
    const float* __restrict__ z,
    const int* __restrict__ pos, const int* __restrict__ neg,
    float* __restrict__ out) {
    int t = blockIdx.x * 256 + threadIdx.x;
    int g = t >> 4;
    int lane = t & 15;
    if (g >= 2 * NEP) return;
    const int* ei;
    int e;
    float* o;
    if (g < NEP) { ei = pos; e = g; o = out; }
    else         { ei = neg; e = g - NEP; o = out + NEP; }
    int a  = ei[e];
    int bn = ei[NEP + e];
    float4 va = *reinterpret_cast<const float4*>(z + (size_t)a  * 64 + lane * 4);
    float4 vb = *reinterpret_cast<const float4*>(z + (size_t)bn * 64 + lane * 4);
    float s = va.x * vb.x + va.y * vb.y + va.z * vb.z + va.w * vb.w;
    s += __shfl_xor(s, 1);
    s += __shfl_xor(s, 2);
    s += __shfl_xor(s, 4);
    s += __shfl_xor(s, 8);
    if (lane == 0) o[e] = s;
}

extern "C" void kernel_launch(void* const* d_in, const int* in_sizes, int n_in,
                              void* d_out, int out_size, void* d_ws, size_t ws_size,
                              hipStream_t stream) {
    const float* x    = (const float*)d_in[0];
    const int*   ei   = (const int*)d_in[1];
    const int*   pos  = (const int*)d_in[2];
    const int*   neg  = (const int*)d_in[3];
    const float* Wl1  = (const float*)d_in[4];
    const float* Wr1  = (const float*)d_in[5];
    const float* b1   = (const float*)d_in[6];
    const float* Wl2  = (const float*)d_in[7];
    const float* Wr2  = (const float*)d_in[8];
    const float* b2   = (const float*)d_in[9];
    float* out = (float*)d_out;

    char* ws = (char*)d_ws;
    float* agg = (float*)(ws);                                  // N*128 floats
    float* deg = (float*)(ws + (size_t)N_NODES * 128 * 4);      // N floats
    float* h   = (float*)(ws + (size_t)N_NODES * 129 * 4);      // N*128 floats
    float* z   = (float*)(ws + (size_t)N_NODES * 257 * 4);      // N*64 floats

    // zero agg + deg (contiguous)
    hipMemsetAsync(agg, 0, (size_t)N_NODES * 129 * 4, stream);

    scatter_kernel<true><<<NE / 4, 256, 0, stream>>>(x, ei, agg, deg);
    l1_kernel<<<N_NODES / 8, 128, 0, stream>>>(x, agg, deg, Wl1, Wr1, b1, h);

    hipMemsetAsync(agg, 0, (size_t)N_NODES * 128 * 4, stream);
    scatter_kernel<false><<<NE / 4, 256, 0, stream>>>(h, ei, agg, deg);
    l2_kernel<<<N_NODES / 8, 64, 0, stream>>>(h, agg, deg, Wl2, Wr2, b2, z);

    decode_kernel<<<(2 * NEP * 16) / 256, 256, 0, stream>>>(z, pos, neg, out);
}

// Round 2
// 429.496 us; speedup vs baseline: 2.5890x; 2.5890x over previous
//
#include <hip/hip_runtime.h>

#define N_NODES 100000
#define IN_C 128
#define HID 128
#define OUTC 64
#define NE 500000
#define NEP 100000
#define NBLK_SCAN ((N_NODES + 255) / 256)   // 391

// ---------------- CSR build ---------------------------------------------------
__global__ __launch_bounds__(256) void hist_kernel(
    const int* __restrict__ ei, int* __restrict__ cnt) {
    int e = blockIdx.x * 256 + threadIdx.x;
    if (e >= NE) return;
    int dst = ei[NE + e];
    atomicAdd(&cnt[dst], 1);
}

// per-256-tile inclusive scan -> local exclusive into off, tile total into sums
__global__ __launch_bounds__(256) void scan1_kernel(
    const int* __restrict__ cnt, int* __restrict__ off, int* __restrict__ sums) {
    __shared__ int buf[256];
    int t = threadIdx.x;
    int i = blockIdx.x * 256 + t;
    int v = (i < N_NODES) ? cnt[i] : 0;
    buf[t] = v;
    __syncthreads();
#pragma unroll
    for (int d = 1; d < 256; d <<= 1) {
        int add = (t >= d) ? buf[t - d] : 0;
        __syncthreads();
        buf[t] += add;
        __syncthreads();
    }
    if (i < N_NODES) off[i] = buf[t] - v;       // exclusive within tile
    if (t == 255) sums[blockIdx.x] = buf[255];  // tile total
}

// single-block exclusive scan of the tile sums (NBLK_SCAN <= 512)
__global__ __launch_bounds__(512) void scan2_kernel(int* __restrict__ sums) {
    __shared__ int buf[512];
    int t = threadIdx.x;
    int v = (t < NBLK_SCAN) ? sums[t] : 0;
    buf[t] = v;
    __syncthreads();
#pragma unroll
    for (int d = 1; d < 512; d <<= 1) {
        int add = (t >= d) ? buf[t - d] : 0;
        __syncthreads();
        buf[t] += add;
        __syncthreads();
    }
    if (t < NBLK_SCAN) sums[t] = buf[t] - v;    // exclusive
}

// add tile offsets; duplicate into off2 (fill cursors); off[N] = NE
__global__ __launch_bounds__(256) void scan3_kernel(
    int* __restrict__ off, int* __restrict__ off2, const int* __restrict__ sums) {
    int i = blockIdx.x * 256 + threadIdx.x;
    if (i >= N_NODES) return;
    int o = off[i] + sums[blockIdx.x];
    off[i] = o;
    off2[i] = o;
    if (i == 0) off[N_NODES] = NE;
}

__global__ __launch_bounds__(256) void fill_kernel(
    const int* __restrict__ ei, int* __restrict__ off2, int* __restrict__ srcS) {
    int e = blockIdx.x * 256 + threadIdx.x;
    if (e >= NE) return;
    int src = ei[e];
    int dst = ei[NE + e];
    int pos = atomicAdd(&off2[dst], 1);
    srcS[pos] = src;
}

// ---------------- gather-aggregate + mean: one wave per node ------------------
__global__ __launch_bounds__(256) void agg_mean_kernel(
    const float* __restrict__ feat,      // [N][128]
    const int* __restrict__ off,         // [N+1]
    const int* __restrict__ srcS,        // [NE]
    float* __restrict__ aggOut) {        // [N][128] = mean
    int n = blockIdx.x * 4 + (threadIdx.x >> 6);
    if (n >= N_NODES) return;
    int lane = threadIdx.x & 63;
    int s0 = off[n], s1 = off[n + 1];
    float ax = 0.0f, ay = 0.0f;
    for (int k = s0; k < s1; ++k) {
        int s = srcS[k];
        float2 v = *reinterpret_cast<const float2*>(feat + (size_t)s * 128 + lane * 2);
        ax += v.x;
        ay += v.y;
    }
    float inv = (s1 > s0) ? 1.0f / (float)(s1 - s0) : 0.0f;
    *reinterpret_cast<float2*>(aggOut + (size_t)n * 128 + lane * 2) =
        make_float2(ax * inv, ay * inv);
}

// ---------------- layer 1: h = relu(mean@Wl + x@Wr + b), 128 outputs ----------
__global__ __launch_bounds__(128) void l1_kernel(
    const float* __restrict__ x, const float* __restrict__ mean,
    const float* __restrict__ Wl, const float* __restrict__ Wr,
    const float* __restrict__ b, float* __restrict__ h) {
    __shared__ float xs[8][128];
    __shared__ float ms[8][128];
    const int j = threadIdx.x;
    const int n0 = blockIdx.x * 8;
#pragma unroll
    for (int nb = 0; nb < 8; ++nb) {
        int n = n0 + nb;
        xs[nb][j] = x[(size_t)n * 128 + j];
        ms[nb][j] = mean[(size_t)n * 128 + j];
    }
    __syncthreads();
    float acc[8];
#pragma unroll
    for (int nb = 0; nb < 8; ++nb) acc[nb] = 0.0f;
    for (int c = 0; c < 128; c += 4) {
        float wl0 = Wl[(c + 0) * 128 + j], wl1 = Wl[(c + 1) * 128 + j];
        float wl2 = Wl[(c + 2) * 128 + j], wl3 = Wl[(c + 3) * 128 + j];
        float wr0 = Wr[(c + 0) * 128 + j], wr1 = Wr[(c + 1) * 128 + j];
        float wr2 = Wr[(c + 2) * 128 + j], wr3 = Wr[(c + 3) * 128 + j];
#pragma unroll
        for (int nb = 0; nb < 8; ++nb) {
            float4 m4 = *reinterpret_cast<const float4*>(&ms[nb][c]);
            float4 x4 = *reinterpret_cast<const float4*>(&xs[nb][c]);
            acc[nb] += m4.x * wl0 + m4.y * wl1 + m4.z * wl2 + m4.w * wl3
                     + x4.x * wr0 + x4.y * wr1 + x4.z * wr2 + x4.w * wr3;
        }
    }
    float bj = b[j];
#pragma unroll
    for (int nb = 0; nb < 8; ++nb) {
        int n = n0 + nb;
        h[(size_t)n * 128 + j] = fmaxf(acc[nb] + bj, 0.0f);
    }
}

// ---------------- layer 2: z = mean@Wl + h@Wr + b, 64 outputs -----------------
__global__ __launch_bounds__(64) void l2_kernel(
    const float* __restrict__ h, const float* __restrict__ mean,
    const float* __restrict__ Wl, const float* __restrict__ Wr,
    const float* __restrict__ b, float* __restrict__ z) {
    __shared__ float hs[8][128];
    __shared__ float ms[8][128];
    const int j = threadIdx.x;  // 0..63
    const int n0 = blockIdx.x * 8;
#pragma unroll
    for (int nb = 0; nb < 8; ++nb) {
        int n = n0 + nb;
        hs[nb][j]      = h[(size_t)n * 128 + j];
        hs[nb][j + 64] = h[(size_t)n * 128 + 64 + j];
        ms[nb][j]      = mean[(size_t)n * 128 + j];
        ms[nb][j + 64] = mean[(size_t)n * 128 + 64 + j];
    }
    __syncthreads();
    float acc[8];
#pragma unroll
    for (int nb = 0; nb < 8; ++nb) acc[nb] = 0.0f;
    for (int c = 0; c < 128; c += 4) {
        float wl0 = Wl[(c + 0) * 64 + j], wl1 = Wl[(c + 1) * 64 + j];
        float wl2 = Wl[(c + 2) * 64 + j], wl3 = Wl[(c + 3) * 64 + j];
        float wr0 = Wr[(c + 0) * 64 + j], wr1 = Wr[(c + 1) * 64 + j];
        float wr2 = Wr[(c + 2) * 64 + j], wr3 = Wr[(c + 3) * 64 + j];
#pragma unroll
        for (int nb = 0; nb < 8; ++nb) {
            float4 m4 = *reinterpret_cast<const float4*>(&ms[nb][c]);
            float4 h4 = *reinterpret_cast<const float4*>(&hs[nb][c]);
            acc[nb] += m4.x * wl0 + m4.y * wl1 + m4.z * wl2 + m4.w * wl3
                     + h4.x * wr0 + h4.y * wr1 + h4.z * wr2 + h4.w * wr3;
        }
    }
    float bj = b[j];
#pragma unroll
    for (int nb = 0; nb < 8; ++nb) {
        int n = n0 + nb;
        z[(size_t)n * 64 + j] = acc[nb] + bj;
    }
}

// ---------------- decode: 16 lanes per edge, dot over 64 dims ------------------
__global__ __launch_bounds__(256) void decode_kernel(
    const float* __restrict__ z,
    const int* __restrict__ pos, const int* __restrict__ neg,
    float* __restrict__ out) {
    int t = blockIdx.x * 256 + threadIdx.x;
    int g = t >> 4;
    int lane = t & 15;
    if (g >= 2 * NEP) return;
    const int* ei;
    int e;
    float* o;
    if (g < NEP) { ei = pos; e = g; o = out; }
    else         { ei = neg; e = g - NEP; o = out + NEP; }
    int a  = ei[e];
    int bn = ei[NEP + e];
    float4 va = *reinterpret_cast<const float4*>(z + (size_t)a  * 64 + lane * 4);
    float4 vb = *reinterpret_cast<const float4*>(z + (size_t)bn * 64 + lane * 4);
    float s = va.x * vb.x + va.y * vb.y + va.z * vb.z + va.w * vb.w;
    s += __shfl_xor(s, 1);
    s += __shfl_xor(s, 2);
    s += __shfl_xor(s, 4);
    s += __shfl_xor(s, 8);
    if (lane == 0) o[e] = s;
}

extern "C" void kernel_launch(void* const* d_in, const int* in_sizes, int n_in,
                              void* d_out, int out_size, void* d_ws, size_t ws_size,
                              hipStream_t stream) {
    const float* x    = (const float*)d_in[0];
    const int*   ei   = (const int*)d_in[1];
    const int*   pos  = (const int*)d_in[2];
    const int*   neg  = (const int*)d_in[3];
    const float* Wl1  = (const float*)d_in[4];
    const float* Wr1  = (const float*)d_in[5];
    const float* b1   = (const float*)d_in[6];
    const float* Wl2  = (const float*)d_in[7];
    const float* Wr2  = (const float*)d_in[8];
    const float* b2   = (const float*)d_in[9];
    float* out = (float*)d_out;

    float* agg  = (float*)d_ws;                 // N*128
    float* h    = agg + (size_t)N_NODES * 128;  // N*128
    float* z    = h   + (size_t)N_NODES * 128;  // N*64
    int*   cnt  = (int*)(z + (size_t)N_NODES * 64);  // N
    int*   off  = cnt + N_NODES;                // N+1
    int*   off2 = off + N_NODES + 1;            // N
    int*   srcS = off2 + N_NODES;               // NE
    int*   sums = srcS + NE;                    // 512

    // ---- CSR build (reused by both layers) ----
    hipMemsetAsync(cnt, 0, N_NODES * sizeof(int), stream);
    hist_kernel <<<(NE + 255) / 256, 256, 0, stream>>>(ei, cnt);
    scan1_kernel<<<NBLK_SCAN, 256, 0, stream>>>(cnt, off, sums);
    scan2_kernel<<<1, 512, 0, stream>>>(sums);
    scan3_kernel<<<NBLK_SCAN, 256, 0, stream>>>(off, off2, sums);
    fill_kernel <<<(NE + 255) / 256, 256, 0, stream>>>(ei, off2, srcS);

    // ---- layer 1 ----
    agg_mean_kernel<<<N_NODES / 4, 256, 0, stream>>>(x, off, srcS, agg);
    l1_kernel<<<N_NODES / 8, 128, 0, stream>>>(x, agg, Wl1, Wr1, b1, h);

    // ---- layer 2 ----
    agg_mean_kernel<<<N_NODES / 4, 256, 0, stream>>>(h, off, srcS, agg);
    l2_kernel<<<N_NODES / 8, 64, 0, stream>>>(h, agg, Wl2, Wr2, b2, z);

    // ---- decode ----
    decode_kernel<<<(2 * NEP * 16) / 256, 256, 0, stream>>>(z, pos, neg, out);
}

// Round 3
// 295.017 us; speedup vs baseline: 3.7691x; 1.4558x over previous
//
#include <hip/hip_runtime.h>

#define N_NODES 100000
#define NE 500000
#define NEP 100000
#define NBLK_SCAN ((N_NODES + 255) / 256)   // 391

typedef short bf16x8 __attribute__((ext_vector_type(8)));
typedef float f32x4  __attribute__((ext_vector_type(4)));

__device__ inline ushort f2bf(float f) {
    uint u = __builtin_bit_cast(uint, f);
    return (ushort)((u + 0x7FFFu + ((u >> 16) & 1u)) >> 16);   // RNE
}
__device__ inline float bf2f(ushort h) {
    uint u = ((uint)h) << 16;
    return __builtin_bit_cast(float, u);
}

// ---------------- CSR build ---------------------------------------------------
__global__ __launch_bounds__(256) void hist_kernel(
    const int* __restrict__ ei, int* __restrict__ cnt) {
    int e = blockIdx.x * 256 + threadIdx.x;
    if (e >= NE) return;
    atomicAdd(&cnt[ei[NE + e]], 1);
}

__global__ __launch_bounds__(256) void scan1_kernel(
    const int* __restrict__ cnt, int* __restrict__ off, int* __restrict__ sums) {
    __shared__ int buf[256];
    int t = threadIdx.x;
    int i = blockIdx.x * 256 + t;
    int v = (i < N_NODES) ? cnt[i] : 0;
    buf[t] = v;
    __syncthreads();
#pragma unroll
    for (int d = 1; d < 256; d <<= 1) {
        int add = (t >= d) ? buf[t - d] : 0;
        __syncthreads();
        buf[t] += add;
        __syncthreads();
    }
    if (i < N_NODES) off[i] = buf[t] - v;
    if (t == 255) sums[blockIdx.x] = buf[255];
}

__global__ __launch_bounds__(512) void scan2_kernel(int* __restrict__ sums) {
    __shared__ int buf[512];
    int t = threadIdx.x;
    int v = (t < NBLK_SCAN) ? sums[t] : 0;
    buf[t] = v;
    __syncthreads();
#pragma unroll
    for (int d = 1; d < 512; d <<= 1) {
        int add = (t >= d) ? buf[t - d] : 0;
        __syncthreads();
        buf[t] += add;
        __syncthreads();
    }
    if (t < NBLK_SCAN) sums[t] = buf[t] - v;
}

__global__ __launch_bounds__(256) void scan3_kernel(
    int* __restrict__ off, int* __restrict__ off2, const int* __restrict__ sums) {
    int i = blockIdx.x * 256 + threadIdx.x;
    if (i >= N_NODES) return;
    int o = off[i] + sums[blockIdx.x];
    off[i] = o;
    off2[i] = o;
    if (i == 0) off[N_NODES] = NE;
}

__global__ __launch_bounds__(256) void fill_kernel(
    const int* __restrict__ ei, int* __restrict__ off2, int* __restrict__ srcS) {
    int e = blockIdx.x * 256 + threadIdx.x;
    if (e >= NE) return;
    int src = ei[e];
    int dst = ei[NE + e];
    int pos = atomicAdd(&off2[dst], 1);
    srcS[pos] = src;
}

// ---------------- gather-aggregate + mean (128-dim, fp32 out) -----------------
__global__ __launch_bounds__(256) void agg_mean_kernel(
    const float* __restrict__ feat, const int* __restrict__ off,
    const int* __restrict__ srcS, float* __restrict__ aggOut) {
    int n = blockIdx.x * 4 + (threadIdx.x >> 6);
    if (n >= N_NODES) return;
    int lane = threadIdx.x & 63;
    int s0 = off[n], s1 = off[n + 1];
    float ax = 0.0f, ay = 0.0f;
    for (int k = s0; k < s1; ++k) {
        int s = srcS[k];
        float2 v = *reinterpret_cast<const float2*>(feat + (size_t)s * 128 + lane * 2);
        ax += v.x;
        ay += v.y;
    }
    float inv = (s1 > s0) ? 1.0f / (float)(s1 - s0) : 0.0f;
    *reinterpret_cast<float2*>(aggOut + (size_t)n * 128 + lane * 2) =
        make_float2(ax * inv, ay * inv);
}

// ---------------- weight packing into MFMA B-fragment order -------------------
// read index in gemm: ((ks*8 + tile)*64 + lane)*8 + r
// element: k = ks*32 + (lane>>4)*8 + r ; n = tile*16 + (lane&15)
__global__ __launch_bounds__(256) void wconv1_kernel(
    const float* __restrict__ Wl, const float* __restrict__ Wr,
    ushort* __restrict__ bh, ushort* __restrict__ bl) {
    int gid = blockIdx.x * 256 + threadIdx.x;      // < 32768
    int r = gid & 7, lane = (gid >> 3) & 63, t = (gid >> 9) & 7, ks = gid >> 12;
    int k = ks * 32 + ((lane >> 4) << 3) + r;
    int n = t * 16 + (lane & 15);
    float v = (k < 128) ? Wl[k * 128 + n] : Wr[(k - 128) * 128 + n];
    ushort h = f2bf(v);
    bh[gid] = h;
    bl[gid] = f2bf(v - bf2f(h));
}

__global__ __launch_bounds__(256) void wconv2_kernel(
    const float* __restrict__ Wl, const float* __restrict__ Wr,
    ushort* __restrict__ bh, ushort* __restrict__ bl) {
    int gid = blockIdx.x * 256 + threadIdx.x;      // < 16384
    int r = gid & 7, lane = (gid >> 3) & 63, t = (gid >> 9) & 7, ks = gid >> 12;
    int k = ks * 32 + ((lane >> 4) << 3) + r;
    int col = t * 16 + (lane & 15);                // 0-63 -> Wl2 (t), 64-127 -> Wr2 (u)
    float v = (col < 64) ? Wl[k * 64 + col] : Wr[k * 64 + (col - 64)];
    ushort h = f2bf(v);
    bh[gid] = h;
    bl[gid] = f2bf(v - bf2f(h));
}

// ---------------- GEMM 1: h = relu([mean|x] @ [Wl1;Wr1] + b1) ------------------
// wave = 32 rows; split-bf16 (3 mfma) for ~fp32 accuracy
__global__ __launch_bounds__(256) void gemm1_kernel(
    const float* __restrict__ mean1, const float* __restrict__ x,
    const ushort* __restrict__ bh, const ushort* __restrict__ bl,
    const float* __restrict__ b1, float* __restrict__ h) {
    int wid = blockIdx.x * 4 + (threadIdx.x >> 6);
    if (wid >= N_NODES / 32) return;
    int lane = threadIdx.x & 63;
    int lrow = lane & 15, kg = lane >> 4;
    size_t r0 = (size_t)wid * 32;
    const f32x4 z4 = {0.f, 0.f, 0.f, 0.f};
    f32x4 acc[2][8];
#pragma unroll
    for (int s = 0; s < 2; ++s)
#pragma unroll
        for (int t = 0; t < 8; ++t) acc[s][t] = z4;
    const bf16x8* bhp = (const bf16x8*)bh;
    const bf16x8* blp = (const bf16x8*)bl;
#pragma unroll
    for (int ks = 0; ks < 8; ++ks) {
        const float* A = (ks < 4) ? (mean1 + ks * 32) : (x + (ks - 4) * 32);
        float a0[8], a1[8];
        *(float4*)&a0[0] = *(const float4*)(A + (r0 + lrow) * 128 + kg * 8);
        *(float4*)&a0[4] = *(const float4*)(A + (r0 + lrow) * 128 + kg * 8 + 4);
        *(float4*)&a1[0] = *(const float4*)(A + (r0 + 16 + lrow) * 128 + kg * 8);
        *(float4*)&a1[4] = *(const float4*)(A + (r0 + 16 + lrow) * 128 + kg * 8 + 4);
        bf16x8 a0h, a0l, a1h, a1l;
#pragma unroll
        for (int i = 0; i < 8; ++i) {
            ushort hh = f2bf(a0[i]);
            a0h[i] = (short)hh; a0l[i] = (short)f2bf(a0[i] - bf2f(hh));
            ushort h2 = f2bf(a1[i]);
            a1h[i] = (short)h2; a1l[i] = (short)f2bf(a1[i] - bf2f(h2));
        }
#pragma unroll
        for (int t = 0; t < 8; ++t) {
            bf16x8 Bh = bhp[(ks * 8 + t) * 64 + lane];
            bf16x8 Bl = blp[(ks * 8 + t) * 64 + lane];
            acc[0][t] = __builtin_amdgcn_mfma_f32_16x16x32_bf16(a0h, Bh, acc[0][t], 0, 0, 0);
            acc[0][t] = __builtin_amdgcn_mfma_f32_16x16x32_bf16(a0l, Bh, acc[0][t], 0, 0, 0);
            acc[0][t] = __builtin_amdgcn_mfma_f32_16x16x32_bf16(a0h, Bl, acc[0][t], 0, 0, 0);
            acc[1][t] = __builtin_amdgcn_mfma_f32_16x16x32_bf16(a1h, Bh, acc[1][t], 0, 0, 0);
            acc[1][t] = __builtin_amdgcn_mfma_f32_16x16x32_bf16(a1l, Bh, acc[1][t], 0, 0, 0);
            acc[1][t] = __builtin_amdgcn_mfma_f32_16x16x32_bf16(a1h, Bl, acc[1][t], 0, 0, 0);
        }
    }
#pragma unroll
    for (int t = 0; t < 8; ++t) {
        float bj = b1[t * 16 + lrow];
#pragma unroll
        for (int s = 0; s < 2; ++s)
#pragma unroll
            for (int rg = 0; rg < 4; ++rg) {
                size_t grow = r0 + s * 16 + kg * 4 + rg;
                h[grow * 128 + t * 16 + lrow] = fmaxf(acc[s][t][rg] + bj, 0.0f);
            }
    }
}

// ---------------- GEMM 2: [t|u] = h @ [Wl2|Wr2] --------------------------------
__global__ __launch_bounds__(256) void gemm2_kernel(
    const float* __restrict__ hin,
    const ushort* __restrict__ bh, const ushort* __restrict__ bl,
    float* __restrict__ tb, float* __restrict__ ub) {
    int wid = blockIdx.x * 4 + (threadIdx.x >> 6);
    if (wid >= N_NODES / 32) return;
    int lane = threadIdx.x & 63;
    int lrow = lane & 15, kg = lane >> 4;
    size_t r0 = (size_t)wid * 32;
    const f32x4 z4 = {0.f, 0.f, 0.f, 0.f};
    f32x4 acc[2][8];
#pragma unroll
    for (int s = 0; s < 2; ++s)
#pragma unroll
        for (int t = 0; t < 8; ++t) acc[s][t] = z4;
    const bf16x8* bhp = (const bf16x8*)bh;
    const bf16x8* blp = (const bf16x8*)bl;
#pragma unroll
    for (int ks = 0; ks < 4; ++ks) {
        const float* A = hin + ks * 32;
        float a0[8], a1[8];
        *(float4*)&a0[0] = *(const float4*)(A + (r0 + lrow) * 128 + kg * 8);
        *(float4*)&a0[4] = *(const float4*)(A + (r0 + lrow) * 128 + kg * 8 + 4);
        *(float4*)&a1[0] = *(const float4*)(A + (r0 + 16 + lrow) * 128 + kg * 8);
        *(float4*)&a1[4] = *(const float4*)(A + (r0 + 16 + lrow) * 128 + kg * 8 + 4);
        bf16x8 a0h, a0l, a1h, a1l;
#pragma unroll
        for (int i = 0; i < 8; ++i) {
            ushort hh = f2bf(a0[i]);
            a0h[i] = (short)hh; a0l[i] = (short)f2bf(a0[i] - bf2f(hh));
            ushort h2 = f2bf(a1[i]);
            a1h[i] = (short)h2; a1l[i] = (short)f2bf(a1[i] - bf2f(h2));
        }
#pragma unroll
        for (int t = 0; t < 8; ++t) {
            bf16x8 Bh = bhp[(ks * 8 + t) * 64 + lane];
            bf16x8 Bl = blp[(ks * 8 + t) * 64 + lane];
            acc[0][t] = __builtin_amdgcn_mfma_f32_16x16x32_bf16(a0h, Bh, acc[0][t], 0, 0, 0);
            acc[0][t] = __builtin_amdgcn_mfma_f32_16x16x32_bf16(a0l, Bh, acc[0][t], 0, 0, 0);
            acc[0][t] = __builtin_amdgcn_mfma_f32_16x16x32_bf16(a0h, Bl, acc[0][t], 0, 0, 0);
            acc[1][t] = __builtin_amdgcn_mfma_f32_16x16x32_bf16(a1h, Bh, acc[1][t], 0, 0, 0);
            acc[1][t] = __builtin_amdgcn_mfma_f32_16x16x32_bf16(a1l, Bh, acc[1][t], 0, 0, 0);
            acc[1][t] = __builtin_amdgcn_mfma_f32_16x16x32_bf16(a1h, Bl, acc[1][t], 0, 0, 0);
        }
    }
#pragma unroll
    for (int t = 0; t < 8; ++t) {
#pragma unroll
        for (int s = 0; s < 2; ++s)
#pragma unroll
            for (int rg = 0; rg < 4; ++rg) {
                size_t grow = r0 + s * 16 + kg * 4 + rg;
                int col = t * 16 + lrow;
                if (t < 4) tb[grow * 64 + col] = acc[s][t][rg];
                else       ub[grow * 64 + (col - 64)] = acc[s][t][rg];
            }
    }
}

// ---------------- layer-2 aggregate (64-dim) + combine: z = mean(t)+u+b2 ------
__global__ __launch_bounds__(256) void agg_z_kernel(
    const float* __restrict__ tb, const float* __restrict__ ub,
    const float* __restrict__ b2, const int* __restrict__ off,
    const int* __restrict__ srcS, float* __restrict__ z) {
    int n = blockIdx.x * 4 + (threadIdx.x >> 6);
    if (n >= N_NODES) return;
    int lane = threadIdx.x & 63;
    int s0 = off[n], s1 = off[n + 1];
    float a = 0.0f;
    for (int k = s0; k < s1; ++k) a += tb[(size_t)srcS[k] * 64 + lane];
    float inv = (s1 > s0) ? 1.0f / (float)(s1 - s0) : 0.0f;
    z[(size_t)n * 64 + lane] = a * inv + ub[(size_t)n * 64 + lane] + b2[lane];
}

// ---------------- decode ------------------------------------------------------
__global__ __launch_bounds__(256) void decode_kernel(
    const float* __restrict__ z,
    const int* __restrict__ pos, const int* __restrict__ neg,
    float* __restrict__ out) {
    int t = blockIdx.x * 256 + threadIdx.x;
    int g = t >> 4;
    int lane = t & 15;
    if (g >= 2 * NEP) return;
    const int* ei;
    int e;
    float* o;
    if (g < NEP) { ei = pos; e = g; o = out; }
    else         { ei = neg; e = g - NEP; o = out + NEP; }
    int a  = ei[e];
    int bn = ei[NEP + e];
    float4 va = *reinterpret_cast<const float4*>(z + (size_t)a  * 64 + lane * 4);
    float4 vb = *reinterpret_cast<const float4*>(z + (size_t)bn * 64 + lane * 4);
    float s = va.x * vb.x + va.y * vb.y + va.z * vb.z + va.w * vb.w;
    s += __shfl_xor(s, 1);
    s += __shfl_xor(s, 2);
    s += __shfl_xor(s, 4);
    s += __shfl_xor(s, 8);
    if (lane == 0) o[e] = s;
}

extern "C" void kernel_launch(void* const* d_in, const int* in_sizes, int n_in,
                              void* d_out, int out_size, void* d_ws, size_t ws_size,
                              hipStream_t stream) {
    const float* x    = (const float*)d_in[0];
    const int*   ei   = (const int*)d_in[1];
    const int*   pos  = (const int*)d_in[2];
    const int*   neg  = (const int*)d_in[3];
    const float* Wl1  = (const float*)d_in[4];
    const float* Wr1  = (const float*)d_in[5];
    const float* b1   = (const float*)d_in[6];
    const float* Wl2  = (const float*)d_in[7];
    const float* Wr2  = (const float*)d_in[8];
    const float* b2   = (const float*)d_in[9];
    float* out = (float*)d_out;

    // bufA (N*128 f32): mean1, later t|u.  bufB (N*128 f32): h, later z.
    float* bufA  = (float*)d_ws;
    float* bufB  = bufA + (size_t)N_NODES * 128;
    float* mean1 = bufA;
    float* tb    = bufA;                          // N*64 (after gemm1, mean1 dead)
    float* ub    = bufA + (size_t)N_NODES * 64;   // N*64
    float* h     = bufB;
    float* z     = bufB;                          // N*64 (after gemm2, h dead)

    int* cnt  = (int*)(bufB + (size_t)N_NODES * 128);
    int* off  = cnt + N_NODES;            // N+1
    int* off2 = off + N_NODES + 1;        // N
    int* srcS = off2 + N_NODES;           // NE
    int* sums = srcS + NE;                // 512
    ushort* b1h = (ushort*)(sums + 512);  // 32768
    ushort* b1l = b1h + 32768;
    ushort* b2h = b1l + 32768;            // 16384
    ushort* b2l = b2h + 16384;

    // ---- CSR build ----
    hipMemsetAsync(cnt, 0, N_NODES * sizeof(int), stream);
    hist_kernel <<<(NE + 255) / 256, 256, 0, stream>>>(ei, cnt);
    scan1_kernel<<<NBLK_SCAN, 256, 0, stream>>>(cnt, off, sums);
    scan2_kernel<<<1, 512, 0, stream>>>(sums);
    scan3_kernel<<<NBLK_SCAN, 256, 0, stream>>>(off, off2, sums);
    fill_kernel <<<(NE + 255) / 256, 256, 0, stream>>>(ei, off2, srcS);

    // ---- weight packing (tiny) ----
    wconv1_kernel<<<128, 256, 0, stream>>>(Wl1, Wr1, b1h, b1l);
    wconv2_kernel<<<64, 256, 0, stream>>>(Wl2, Wr2, b2h, b2l);

    // ---- layer 1 ----
    agg_mean_kernel<<<N_NODES / 4, 256, 0, stream>>>(x, off, srcS, mean1);
    gemm1_kernel<<<(N_NODES / 32 + 3) / 4, 256, 0, stream>>>(mean1, x, b1h, b1l, b1, h);

    // ---- layer 2 (transform-then-aggregate) ----
    gemm2_kernel<<<(N_NODES / 32 + 3) / 4, 256, 0, stream>>>(h, b2h, b2l, tb, ub);
    agg_z_kernel<<<N_NODES / 4, 256, 0, stream>>>(tb, ub, b2, off, srcS, z);

    // ---- decode ----
    decode_kernel<<<(2 * NEP * 16) / 256, 256, 0, stream>>>(z, pos, neg, out);
}

// Round 4
// 243.952 us; speedup vs baseline: 4.5581x; 1.2093x over previous
//
#include <hip/hip_runtime.h>

#define N_NODES 100000
#define NE 500000
#define NEP 100000
#define NBLK_SCAN ((N_NODES + 255) / 256)   // 391

typedef short bf16x8 __attribute__((ext_vector_type(8)));
typedef float f32x4  __attribute__((ext_vector_type(4)));

__device__ inline ushort f2bf(float f) {
    uint u = __builtin_bit_cast(uint, f);
    return (ushort)((u + 0x7FFFu + ((u >> 16) & 1u)) >> 16);   // RNE
}
__device__ inline float bf2f(ushort h) {
    uint u = ((uint)h) << 16;
    return __builtin_bit_cast(float, u);
}
__device__ inline float bflo(uint v) { return __builtin_bit_cast(float, v << 16); }
__device__ inline float bfhi(uint v) { return __builtin_bit_cast(float, v & 0xFFFF0000u); }

// ---------------- CSR build ---------------------------------------------------
__global__ __launch_bounds__(256) void hist_kernel(
    const int* __restrict__ ei, int* __restrict__ cnt) {
    int e = blockIdx.x * 256 + threadIdx.x;
    if (e >= NE) return;
    atomicAdd(&cnt[ei[NE + e]], 1);
}

__global__ __launch_bounds__(256) void scan1_kernel(
    const int* __restrict__ cnt, int* __restrict__ off, int* __restrict__ sums) {
    __shared__ int buf[256];
    int t = threadIdx.x;
    int i = blockIdx.x * 256 + t;
    int v = (i < N_NODES) ? cnt[i] : 0;
    buf[t] = v;
    __syncthreads();
#pragma unroll
    for (int d = 1; d < 256; d <<= 1) {
        int add = (t >= d) ? buf[t - d] : 0;
        __syncthreads();
        buf[t] += add;
        __syncthreads();
    }
    if (i < N_NODES) off[i] = buf[t] - v;
    if (t == 255) sums[blockIdx.x] = buf[255];
}

__global__ __launch_bounds__(512) void scan2_kernel(int* __restrict__ sums) {
    __shared__ int buf[512];
    int t = threadIdx.x;
    int v = (t < NBLK_SCAN) ? sums[t] : 0;
    buf[t] = v;
    __syncthreads();
#pragma unroll
    for (int d = 1; d < 512; d <<= 1) {
        int add = (t >= d) ? buf[t - d] : 0;
        __syncthreads();
        buf[t] += add;
        __syncthreads();
    }
    if (t < NBLK_SCAN) sums[t] = buf[t] - v;
}

__global__ __launch_bounds__(256) void scan3_kernel(
    int* __restrict__ off, int* __restrict__ off2, const int* __restrict__ sums) {
    int i = blockIdx.x * 256 + threadIdx.x;
    if (i >= N_NODES) return;
    int o = off[i] + sums[blockIdx.x];
    off[i] = o;
    off2[i] = o;
    if (i == 0) off[N_NODES] = NE;
}

__global__ __launch_bounds__(256) void fill_kernel(
    const int* __restrict__ ei, int* __restrict__ off2, int* __restrict__ srcS) {
    int e = blockIdx.x * 256 + threadIdx.x;
    if (e >= NE) return;
    int src = ei[e];
    int dst = ei[NE + e];
    int pos = atomicAdd(&off2[dst], 1);
    srcS[pos] = src;
}

// ---------------- x -> bf16 copy ----------------------------------------------
__global__ __launch_bounds__(256) void xconv_kernel(
    const float* __restrict__ x, ushort* __restrict__ xb) {
    size_t i = ((size_t)blockIdx.x * 256 + threadIdx.x) * 4;   // 12.8M elems, exact
    float4 v = *reinterpret_cast<const float4*>(x + i);
    ushort4 o;
    o.x = f2bf(v.x); o.y = f2bf(v.y); o.z = f2bf(v.z); o.w = f2bf(v.w);
    *reinterpret_cast<ushort4*>(xb + i) = o;
}

// ---------------- layer-1 gather mean over bf16 x (chunk-4 MLP) ---------------
__global__ __launch_bounds__(256) void agg_mean_kernel(
    const ushort* __restrict__ xb, const int* __restrict__ off,
    const int* __restrict__ srcS, float* __restrict__ mean1) {
    int n = blockIdx.x * 4 + (threadIdx.x >> 6);
    if (n >= N_NODES) return;
    int lane = threadIdx.x & 63;
    int s0 = off[n], s1 = off[n + 1];
    float ax = 0.0f, ay = 0.0f;
    int k = s0;
    for (; k + 4 <= s1; k += 4) {
        int sa = srcS[k], sb = srcS[k + 1], sc = srcS[k + 2], sd = srcS[k + 3];
        uint va = *(const uint*)(xb + (size_t)sa * 128 + lane * 2);
        uint vb = *(const uint*)(xb + (size_t)sb * 128 + lane * 2);
        uint vc = *(const uint*)(xb + (size_t)sc * 128 + lane * 2);
        uint vd = *(const uint*)(xb + (size_t)sd * 128 + lane * 2);
        ax += bflo(va) + bflo(vb) + bflo(vc) + bflo(vd);
        ay += bfhi(va) + bfhi(vb) + bfhi(vc) + bfhi(vd);
    }
    for (; k < s1; ++k) {
        uint v = *(const uint*)(xb + (size_t)srcS[k] * 128 + lane * 2);
        ax += bflo(v);
        ay += bfhi(v);
    }
    float inv = (s1 > s0) ? 1.0f / (float)(s1 - s0) : 0.0f;
    *reinterpret_cast<float2*>(mean1 + (size_t)n * 128 + lane * 2) =
        make_float2(ax * inv, ay * inv);
}

// ---------------- weight packing into MFMA B-fragment order -------------------
__global__ __launch_bounds__(256) void wconv1_kernel(
    const float* __restrict__ Wl, const float* __restrict__ Wr,
    ushort* __restrict__ bh, ushort* __restrict__ bl) {
    int gid = blockIdx.x * 256 + threadIdx.x;      // < 32768
    int r = gid & 7, lane = (gid >> 3) & 63, t = (gid >> 9) & 7, ks = gid >> 12;
    int k = ks * 32 + ((lane >> 4) << 3) + r;
    int n = t * 16 + (lane & 15);
    float v = (k < 128) ? Wl[k * 128 + n] : Wr[(k - 128) * 128 + n];
    ushort h = f2bf(v);
    bh[gid] = h;
    bl[gid] = f2bf(v - bf2f(h));
}

__global__ __launch_bounds__(256) void wconv2_kernel(
    const float* __restrict__ Wl, const float* __restrict__ Wr,
    ushort* __restrict__ bh, ushort* __restrict__ bl) {
    int gid = blockIdx.x * 256 + threadIdx.x;      // < 16384
    int r = gid & 7, lane = (gid >> 3) & 63, t = (gid >> 9) & 7, ks = gid >> 12;
    int k = ks * 32 + ((lane >> 4) << 3) + r;
    int col = t * 16 + (lane & 15);
    float v = (col < 64) ? Wl[k * 64 + col] : Wr[k * 64 + (col - 64)];
    ushort h = f2bf(v);
    bh[gid] = h;
    bl[gid] = f2bf(v - bf2f(h));
}

// ---------------- GEMM 1: h = relu([mean|x] @ [Wl1;Wr1] + b1) ------------------
__global__ __launch_bounds__(256) void gemm1_kernel(
    const float* __restrict__ mean1, const float* __restrict__ x,
    const ushort* __restrict__ bh, const ushort* __restrict__ bl,
    const float* __restrict__ b1, float* __restrict__ h) {
    int wid = blockIdx.x * 4 + (threadIdx.x >> 6);
    if (wid >= N_NODES / 32) return;
    int lane = threadIdx.x & 63;
    int lrow = lane & 15, kg = lane >> 4;
    size_t r0 = (size_t)wid * 32;
    const f32x4 z4 = {0.f, 0.f, 0.f, 0.f};
    f32x4 acc[2][8];
#pragma unroll
    for (int s = 0; s < 2; ++s)
#pragma unroll
        for (int t = 0; t < 8; ++t) acc[s][t] = z4;
    const bf16x8* bhp = (const bf16x8*)bh;
    const bf16x8* blp = (const bf16x8*)bl;
#pragma unroll
    for (int ks = 0; ks < 8; ++ks) {
        const float* A = (ks < 4) ? (mean1 + ks * 32) : (x + (ks - 4) * 32);
        float a0[8], a1[8];
        *(float4*)&a0[0] = *(const float4*)(A + (r0 + lrow) * 128 + kg * 8);
        *(float4*)&a0[4] = *(const float4*)(A + (r0 + lrow) * 128 + kg * 8 + 4);
        *(float4*)&a1[0] = *(const float4*)(A + (r0 + 16 + lrow) * 128 + kg * 8);
        *(float4*)&a1[4] = *(const float4*)(A + (r0 + 16 + lrow) * 128 + kg * 8 + 4);
        bf16x8 a0h, a0l, a1h, a1l;
#pragma unroll
        for (int i = 0; i < 8; ++i) {
            ushort hh = f2bf(a0[i]);
            a0h[i] = (short)hh; a0l[i] = (short)f2bf(a0[i] - bf2f(hh));
            ushort h2 = f2bf(a1[i]);
            a1h[i] = (short)h2; a1l[i] = (short)f2bf(a1[i] - bf2f(h2));
        }
#pragma unroll
        for (int t = 0; t < 8; ++t) {
            bf16x8 Bh = bhp[(ks * 8 + t) * 64 + lane];
            bf16x8 Bl = blp[(ks * 8 + t) * 64 + lane];
            acc[0][t] = __builtin_amdgcn_mfma_f32_16x16x32_bf16(a0h, Bh, acc[0][t], 0, 0, 0);
            acc[0][t] = __builtin_amdgcn_mfma_f32_16x16x32_bf16(a0l, Bh, acc[0][t], 0, 0, 0);
            acc[0][t] = __builtin_amdgcn_mfma_f32_16x16x32_bf16(a0h, Bl, acc[0][t], 0, 0, 0);
            acc[1][t] = __builtin_amdgcn_mfma_f32_16x16x32_bf16(a1h, Bh, acc[1][t], 0, 0, 0);
            acc[1][t] = __builtin_amdgcn_mfma_f32_16x16x32_bf16(a1l, Bh, acc[1][t], 0, 0, 0);
            acc[1][t] = __builtin_amdgcn_mfma_f32_16x16x32_bf16(a1h, Bl, acc[1][t], 0, 0, 0);
        }
    }
#pragma unroll
    for (int t = 0; t < 8; ++t) {
        float bj = b1[t * 16 + lrow];
#pragma unroll
        for (int s = 0; s < 2; ++s)
#pragma unroll
            for (int rg = 0; rg < 4; ++rg) {
                size_t grow = r0 + s * 16 + kg * 4 + rg;
                h[grow * 128 + t * 16 + lrow] = fmaxf(acc[s][t][rg] + bj, 0.0f);
            }
    }
}

// ---------------- GEMM 2: [t|u] = h @ [Wl2|Wr2]; t stored bf16 -----------------
__global__ __launch_bounds__(256) void gemm2_kernel(
    const float* __restrict__ hin,
    const ushort* __restrict__ bh, const ushort* __restrict__ bl,
    ushort* __restrict__ tb, float* __restrict__ ub) {
    int wid = blockIdx.x * 4 + (threadIdx.x >> 6);
    if (wid >= N_NODES / 32) return;
    int lane = threadIdx.x & 63;
    int lrow = lane & 15, kg = lane >> 4;
    size_t r0 = (size_t)wid * 32;
    const f32x4 z4 = {0.f, 0.f, 0.f, 0.f};
    f32x4 acc[2][8];
#pragma unroll
    for (int s = 0; s < 2; ++s)
#pragma unroll
        for (int t = 0; t < 8; ++t) acc[s][t] = z4;
    const bf16x8* bhp = (const bf16x8*)bh;
    const bf16x8* blp = (const bf16x8*)bl;
#pragma unroll
    for (int ks = 0; ks < 4; ++ks) {
        const float* A = hin + ks * 32;
        float a0[8], a1[8];
        *(float4*)&a0[0] = *(const float4*)(A + (r0 + lrow) * 128 + kg * 8);
        *(float4*)&a0[4] = *(const float4*)(A + (r0 + lrow) * 128 + kg * 8 + 4);
        *(float4*)&a1[0] = *(const float4*)(A + (r0 + 16 + lrow) * 128 + kg * 8);
        *(float4*)&a1[4] = *(const float4*)(A + (r0 + 16 + lrow) * 128 + kg * 8 + 4);
        bf16x8 a0h, a0l, a1h, a1l;
#pragma unroll
        for (int i = 0; i < 8; ++i) {
            ushort hh = f2bf(a0[i]);
            a0h[i] = (short)hh; a0l[i] = (short)f2bf(a0[i] - bf2f(hh));
            ushort h2 = f2bf(a1[i]);
            a1h[i] = (short)h2; a1l[i] = (short)f2bf(a1[i] - bf2f(h2));
        }
#pragma unroll
        for (int t = 0; t < 8; ++t) {
            bf16x8 Bh = bhp[(ks * 8 + t) * 64 + lane];
            bf16x8 Bl = blp[(ks * 8 + t) * 64 + lane];
            acc[0][t] = __builtin_amdgcn_mfma_f32_16x16x32_bf16(a0h, Bh, acc[0][t], 0, 0, 0);
            acc[0][t] = __builtin_amdgcn_mfma_f32_16x16x32_bf16(a0l, Bh, acc[0][t], 0, 0, 0);
            acc[0][t] = __builtin_amdgcn_mfma_f32_16x16x32_bf16(a0h, Bl, acc[0][t], 0, 0, 0);
            acc[1][t] = __builtin_amdgcn_mfma_f32_16x16x32_bf16(a1h, Bh, acc[1][t], 0, 0, 0);
            acc[1][t] = __builtin_amdgcn_mfma_f32_16x16x32_bf16(a1l, Bh, acc[1][t], 0, 0, 0);
            acc[1][t] = __builtin_amdgcn_mfma_f32_16x16x32_bf16(a1h, Bl, acc[1][t], 0, 0, 0);
        }
    }
#pragma unroll
    for (int t = 0; t < 8; ++t) {
#pragma unroll
        for (int s = 0; s < 2; ++s)
#pragma unroll
            for (int rg = 0; rg < 4; ++rg) {
                size_t grow = r0 + s * 16 + kg * 4 + rg;
                int col = t * 16 + lrow;
                if (t < 4) tb[grow * 64 + col] = f2bf(acc[s][t][rg]);
                else       ub[grow * 64 + (col - 64)] = acc[s][t][rg];
            }
    }
}

// ------- layer-2 gather (bf16 t, chunk-4) + combine: z = mean(t)+u+b2 ---------
__global__ __launch_bounds__(256) void agg_z_kernel(
    const ushort* __restrict__ tb, const float* __restrict__ ub,
    const float* __restrict__ b2, const int* __restrict__ off,
    const int* __restrict__ srcS, ushort* __restrict__ zb) {
    int n = blockIdx.x * 8 + (threadIdx.x >> 5);   // 2 nodes per wave
    if (n >= N_NODES) return;
    int l = threadIdx.x & 31;                      // channels 2l, 2l+1
    int s0 = off[n], s1 = off[n + 1];
    float ax = 0.0f, ay = 0.0f;
    int k = s0;
    for (; k + 4 <= s1; k += 4) {
        int sa = srcS[k], sb = srcS[k + 1], sc = srcS[k + 2], sd = srcS[k + 3];
        uint va = *(const uint*)(tb + (size_t)sa * 64 + l * 2);
        uint vb = *(const uint*)(tb + (size_t)sb * 64 + l * 2);
        uint vc = *(const uint*)(tb + (size_t)sc * 64 + l * 2);
        uint vd = *(const uint*)(tb + (size_t)sd * 64 + l * 2);
        ax += bflo(va) + bflo(vb) + bflo(vc) + bflo(vd);
        ay += bfhi(va) + bfhi(vb) + bfhi(vc) + bfhi(vd);
    }
    for (; k < s1; ++k) {
        uint v = *(const uint*)(tb + (size_t)srcS[k] * 64 + l * 2);
        ax += bflo(v);
        ay += bfhi(v);
    }
    float inv = (s1 > s0) ? 1.0f / (float)(s1 - s0) : 0.0f;
    float2 u = *reinterpret_cast<const float2*>(ub + (size_t)n * 64 + l * 2);
    float zx = ax * inv + u.x + b2[l * 2];
    float zy = ay * inv + u.y + b2[l * 2 + 1];
    uint pz = (uint)f2bf(zx) | ((uint)f2bf(zy) << 16);
    *(uint*)(zb + (size_t)n * 64 + l * 2) = pz;
}

// ---------------- decode over bf16 z ------------------------------------------
__global__ __launch_bounds__(256) void decode_kernel(
    const ushort* __restrict__ zb,
    const int* __restrict__ pos, const int* __restrict__ neg,
    float* __restrict__ out) {
    int t = blockIdx.x * 256 + threadIdx.x;
    int g = t >> 4;
    int lane = t & 15;
    if (g >= 2 * NEP) return;
    const int* ei;
    int e;
    float* o;
    if (g < NEP) { ei = pos; e = g; o = out; }
    else         { ei = neg; e = g - NEP; o = out + NEP; }
    int a  = ei[e];
    int bn = ei[NEP + e];
    ushort4 va = *reinterpret_cast<const ushort4*>(zb + (size_t)a  * 64 + lane * 4);
    ushort4 vb = *reinterpret_cast<const ushort4*>(zb + (size_t)bn * 64 + lane * 4);
    float s = bf2f(va.x) * bf2f(vb.x) + bf2f(va.y) * bf2f(vb.y)
            + bf2f(va.z) * bf2f(vb.z) + bf2f(va.w) * bf2f(vb.w);
    s += __shfl_xor(s, 1);
    s += __shfl_xor(s, 2);
    s += __shfl_xor(s, 4);
    s += __shfl_xor(s, 8);
    if (lane == 0) o[e] = s;
}

extern "C" void kernel_launch(void* const* d_in, const int* in_sizes, int n_in,
                              void* d_out, int out_size, void* d_ws, size_t ws_size,
                              hipStream_t stream) {
    const float* x    = (const float*)d_in[0];
    const int*   ei   = (const int*)d_in[1];
    const int*   pos  = (const int*)d_in[2];
    const int*   neg  = (const int*)d_in[3];
    const float* Wl1  = (const float*)d_in[4];
    const float* Wr1  = (const float*)d_in[5];
    const float* b1   = (const float*)d_in[6];
    const float* Wl2  = (const float*)d_in[7];
    const float* Wr2  = (const float*)d_in[8];
    const float* b2   = (const float*)d_in[9];
    float* out = (float*)d_out;

    const size_t R1 = (size_t)N_NODES * 128 * 4;   // 51.2 MB region size
    char* ws = (char*)d_ws;
    // region1: xb (bf16 x) then reused by h
    ushort* xb = (ushort*)ws;                                   // N*128 bf16
    float*  h  = (float*)ws;                                    // N*128 f32
    // region2: mean1 then reused by tb|ub|zb (12.8+25.6+12.8 = 51.2 MB exactly)
    float*  mean1 = (float*)(ws + R1);                          // N*128 f32
    ushort* tb    = (ushort*)(ws + R1);                         // N*64 bf16
    float*  ub    = (float*)(ws + R1 + (size_t)N_NODES * 64 * 2);
    ushort* zb    = (ushort*)(ws + R1 + (size_t)N_NODES * 64 * 6);
    // ints + packed weights
    int* cnt  = (int*)(ws + 2 * R1);
    int* off  = cnt + N_NODES;
    int* off2 = off + N_NODES + 1;
    int* srcS = off2 + N_NODES;
    int* sums = srcS + NE;
    ushort* b1h = (ushort*)(sums + 512);
    ushort* b1l = b1h + 32768;
    ushort* b2h = b1l + 32768;
    ushort* b2l = b2h + 16384;

    // ---- CSR build ----
    hipMemsetAsync(cnt, 0, N_NODES * sizeof(int), stream);
    hist_kernel <<<(NE + 255) / 256, 256, 0, stream>>>(ei, cnt);
    scan1_kernel<<<NBLK_SCAN, 256, 0, stream>>>(cnt, off, sums);
    scan2_kernel<<<1, 512, 0, stream>>>(sums);
    scan3_kernel<<<NBLK_SCAN, 256, 0, stream>>>(off, off2, sums);
    fill_kernel <<<(NE + 255) / 256, 256, 0, stream>>>(ei, off2, srcS);

    // ---- weight packing + x->bf16 ----
    wconv1_kernel<<<128, 256, 0, stream>>>(Wl1, Wr1, b1h, b1l);
    wconv2_kernel<<<64, 256, 0, stream>>>(Wl2, Wr2, b2h, b2l);
    xconv_kernel<<<12500, 256, 0, stream>>>(x, xb);

    // ---- layer 1 ----
    agg_mean_kernel<<<N_NODES / 4, 256, 0, stream>>>(xb, off, srcS, mean1);
    gemm1_kernel<<<(N_NODES / 32 + 3) / 4, 256, 0, stream>>>(mean1, x, b1h, b1l, b1, h);

    // ---- layer 2 (transform-then-aggregate) ----
    gemm2_kernel<<<(N_NODES / 32 + 3) / 4, 256, 0, stream>>>(h, b2h, b2l, tb, ub);
    agg_z_kernel<<<(N_NODES + 7) / 8, 256, 0, stream>>>(tb, ub, b2, off, srcS, zb);

    // ---- decode ----
    decode_kernel<<<(2 * NEP * 16) / 256, 256, 0, stream>>>(zb, pos, neg, out);
}

// Round 5
// 217.733 us; speedup vs baseline: 5.1069x; 1.1204x over previous
//
#include <hip/hip_runtime.h>

#define N_NODES 100000
#define NE 500000
#define NEP 100000
#define NBLK_SCAN ((N_NODES + 255) / 256)   // 391

typedef short bf16x8 __attribute__((ext_vector_type(8)));
typedef float f32x4  __attribute__((ext_vector_type(4)));

__device__ inline ushort f2bf(float f) {
    uint u = __builtin_bit_cast(uint, f);
    return (ushort)((u + 0x7FFFu + ((u >> 16) & 1u)) >> 16);   // RNE
}
__device__ inline float bf2f(ushort h) {
    uint u = ((uint)h) << 16;
    return __builtin_bit_cast(float, u);
}
__device__ inline float bflo(uint v) { return __builtin_bit_cast(float, v << 16); }
__device__ inline float bfhi(uint v) { return __builtin_bit_cast(float, v & 0xFFFF0000u); }

// ---------------- CSR build ---------------------------------------------------
__global__ __launch_bounds__(256) void hist_kernel(
    const int* __restrict__ ei, int* __restrict__ cnt) {
    int e = blockIdx.x * 256 + threadIdx.x;
    if (e >= NE) return;
    atomicAdd(&cnt[ei[NE + e]], 1);
}

__global__ __launch_bounds__(256) void scan1_kernel(
    const int* __restrict__ cnt, int* __restrict__ off, int* __restrict__ sums) {
    __shared__ int buf[256];
    int t = threadIdx.x;
    int i = blockIdx.x * 256 + t;
    int v = (i < N_NODES) ? cnt[i] : 0;
    buf[t] = v;
    __syncthreads();
#pragma unroll
    for (int d = 1; d < 256; d <<= 1) {
        int add = (t >= d) ? buf[t - d] : 0;
        __syncthreads();
        buf[t] += add;
        __syncthreads();
    }
    if (i < N_NODES) off[i] = buf[t] - v;
    if (t == 255) sums[blockIdx.x] = buf[255];
}

__global__ __launch_bounds__(512) void scan2_kernel(int* __restrict__ sums) {
    __shared__ int buf[512];
    int t = threadIdx.x;
    int v = (t < NBLK_SCAN) ? sums[t] : 0;
    buf[t] = v;
    __syncthreads();
#pragma unroll
    for (int d = 1; d < 512; d <<= 1) {
        int add = (t >= d) ? buf[t - d] : 0;
        __syncthreads();
        buf[t] += add;
        __syncthreads();
    }
    if (t < NBLK_SCAN) sums[t] = buf[t] - v;
}

__global__ __launch_bounds__(256) void scan3_kernel(
    int* __restrict__ off, int* __restrict__ off2, const int* __restrict__ sums) {
    int i = blockIdx.x * 256 + threadIdx.x;
    if (i >= N_NODES) return;
    int o = off[i] + sums[blockIdx.x];
    off[i] = o;
    off2[i] = o;
    if (i == 0) off[N_NODES] = NE;
}

__global__ __launch_bounds__(256) void fill_kernel(
    const int* __restrict__ ei, int* __restrict__ off2, int* __restrict__ srcS) {
    int e = blockIdx.x * 256 + threadIdx.x;
    if (e >= NE) return;
    int src = ei[e];
    int dst = ei[NE + e];
    int pos = atomicAdd(&off2[dst], 1);
    srcS[pos] = src;
}

// ---------------- x -> bf16 copy ----------------------------------------------
__global__ __launch_bounds__(256) void xconv_kernel(
    const float* __restrict__ x, ushort* __restrict__ xb) {
    size_t i = ((size_t)blockIdx.x * 256 + threadIdx.x) * 4;   // 12.8M elems, exact
    float4 v = *reinterpret_cast<const float4*>(x + i);
    ushort4 o;
    o.x = f2bf(v.x); o.y = f2bf(v.y); o.z = f2bf(v.z); o.w = f2bf(v.w);
    *reinterpret_cast<ushort4*>(xb + i) = o;
}

// ------- layer-1 gather mean over bf16 x; writes hi/lo bf16 planes ------------
__global__ __launch_bounds__(256) void agg_mean_kernel(
    const ushort* __restrict__ xb, const int* __restrict__ off,
    const int* __restrict__ srcS, ushort* __restrict__ meanH,
    ushort* __restrict__ meanL) {
    int n = blockIdx.x * 4 + (threadIdx.x >> 6);
    if (n >= N_NODES) return;
    int lane = threadIdx.x & 63;
    int s0 = off[n], s1 = off[n + 1];
    float ax = 0.0f, ay = 0.0f;
    int k = s0;
    for (; k + 4 <= s1; k += 4) {
        int sa = srcS[k], sb = srcS[k + 1], sc = srcS[k + 2], sd = srcS[k + 3];
        uint va = *(const uint*)(xb + (size_t)sa * 128 + lane * 2);
        uint vb = *(const uint*)(xb + (size_t)sb * 128 + lane * 2);
        uint vc = *(const uint*)(xb + (size_t)sc * 128 + lane * 2);
        uint vd = *(const uint*)(xb + (size_t)sd * 128 + lane * 2);
        ax += bflo(va) + bflo(vb) + bflo(vc) + bflo(vd);
        ay += bfhi(va) + bfhi(vb) + bfhi(vc) + bfhi(vd);
    }
    for (; k < s1; ++k) {
        uint v = *(const uint*)(xb + (size_t)srcS[k] * 128 + lane * 2);
        ax += bflo(v);
        ay += bfhi(v);
    }
    float inv = (s1 > s0) ? 1.0f / (float)(s1 - s0) : 0.0f;
    float mx = ax * inv, my = ay * inv;
    ushort hx = f2bf(mx), hy = f2bf(my);
    ushort lx = f2bf(mx - bf2f(hx)), ly = f2bf(my - bf2f(hy));
    *(uint*)(meanH + (size_t)n * 128 + lane * 2) = (uint)hx | ((uint)hy << 16);
    *(uint*)(meanL + (size_t)n * 128 + lane * 2) = (uint)lx | ((uint)ly << 16);
}

// ---------------- weight packing into MFMA B-fragment order -------------------
__global__ __launch_bounds__(256) void wconv1_kernel(
    const float* __restrict__ Wl, const float* __restrict__ Wr,
    ushort* __restrict__ bh, ushort* __restrict__ bl) {
    int gid = blockIdx.x * 256 + threadIdx.x;      // < 32768
    int r = gid & 7, lane = (gid >> 3) & 63, t = (gid >> 9) & 7, ks = gid >> 12;
    int k = ks * 32 + ((lane >> 4) << 3) + r;
    int n = t * 16 + (lane & 15);
    float v = (k < 128) ? Wl[k * 128 + n] : Wr[(k - 128) * 128 + n];
    ushort h = f2bf(v);
    bh[gid] = h;
    bl[gid] = f2bf(v - bf2f(h));
}

__global__ __launch_bounds__(256) void wconv2_kernel(
    const float* __restrict__ Wl, const float* __restrict__ Wr,
    ushort* __restrict__ bh, ushort* __restrict__ bl) {
    int gid = blockIdx.x * 256 + threadIdx.x;      // < 16384
    int r = gid & 7, lane = (gid >> 3) & 63, t = (gid >> 9) & 7, ks = gid >> 12;
    int k = ks * 32 + ((lane >> 4) << 3) + r;
    int col = t * 16 + (lane & 15);
    float v = (col < 64) ? Wl[k * 64 + col] : Wr[k * 64 + (col - 64)];
    ushort h = f2bf(v);
    bh[gid] = h;
    bl[gid] = f2bf(v - bf2f(h));
}

// ------- GEMM 1: h = relu([mean|x] @ [Wl1;Wr1] + b1), 16 rows/wave, bf16 out --
__global__ __launch_bounds__(256) void gemm1_kernel(
    const ushort* __restrict__ meanH, const ushort* __restrict__ meanL,
    const ushort* __restrict__ xb,
    const ushort* __restrict__ bh, const ushort* __restrict__ bl,
    const float* __restrict__ b1, ushort* __restrict__ hb) {
    int wid = blockIdx.x * 4 + (threadIdx.x >> 6);
    if (wid >= N_NODES / 16) return;
    int lane = threadIdx.x & 63;
    int lrow = lane & 15, kg = lane >> 4;
    size_t r0 = (size_t)wid * 16;
    const f32x4 z4 = {0.f, 0.f, 0.f, 0.f};
    f32x4 acc[8];
#pragma unroll
    for (int t = 0; t < 8; ++t) acc[t] = z4;
    const bf16x8* bhp = (const bf16x8*)bh;
    const bf16x8* blp = (const bf16x8*)bl;
#pragma unroll
    for (int ks = 0; ks < 8; ++ks) {
        bf16x8 aH, aL;
        if (ks < 4) {
            aH = *(const bf16x8*)(meanH + (r0 + lrow) * 128 + ks * 32 + kg * 8);
            aL = *(const bf16x8*)(meanL + (r0 + lrow) * 128 + ks * 32 + kg * 8);
        } else {
            aH = *(const bf16x8*)(xb + (r0 + lrow) * 128 + (ks - 4) * 32 + kg * 8);
        }
#pragma unroll
        for (int t = 0; t < 8; ++t) {
            bf16x8 Bh = bhp[(ks * 8 + t) * 64 + lane];
            bf16x8 Bl = blp[(ks * 8 + t) * 64 + lane];
            acc[t] = __builtin_amdgcn_mfma_f32_16x16x32_bf16(aH, Bh, acc[t], 0, 0, 0);
            acc[t] = __builtin_amdgcn_mfma_f32_16x16x32_bf16(aH, Bl, acc[t], 0, 0, 0);
            if (ks < 4)
                acc[t] = __builtin_amdgcn_mfma_f32_16x16x32_bf16(aL, Bh, acc[t], 0, 0, 0);
        }
    }
#pragma unroll
    for (int t = 0; t < 8; ++t) {
        float bj = b1[t * 16 + lrow];
#pragma unroll
        for (int rg = 0; rg < 4; ++rg) {
            size_t row = r0 + kg * 4 + rg;
            hb[row * 128 + t * 16 + lrow] = f2bf(fmaxf(acc[t][rg] + bj, 0.0f));
        }
    }
}

// ------- GEMM 2: [t|u] = h @ [Wl2|Wr2], 16 rows/wave, bf16 in/out -------------
__global__ __launch_bounds__(256) void gemm2_kernel(
    const ushort* __restrict__ hb,
    const ushort* __restrict__ bh, const ushort* __restrict__ bl,
    ushort* __restrict__ tb, ushort* __restrict__ ub) {
    int wid = blockIdx.x * 4 + (threadIdx.x >> 6);
    if (wid >= N_NODES / 16) return;
    int lane = threadIdx.x & 63;
    int lrow = lane & 15, kg = lane >> 4;
    size_t r0 = (size_t)wid * 16;
    const f32x4 z4 = {0.f, 0.f, 0.f, 0.f};
    f32x4 acc[8];
#pragma unroll
    for (int t = 0; t < 8; ++t) acc[t] = z4;
    const bf16x8* bhp = (const bf16x8*)bh;
    const bf16x8* blp = (const bf16x8*)bl;
#pragma unroll
    for (int ks = 0; ks < 4; ++ks) {
        bf16x8 aH = *(const bf16x8*)(hb + (r0 + lrow) * 128 + ks * 32 + kg * 8);
#pragma unroll
        for (int t = 0; t < 8; ++t) {
            bf16x8 Bh = bhp[(ks * 8 + t) * 64 + lane];
            bf16x8 Bl = blp[(ks * 8 + t) * 64 + lane];
            acc[t] = __builtin_amdgcn_mfma_f32_16x16x32_bf16(aH, Bh, acc[t], 0, 0, 0);
            acc[t] = __builtin_amdgcn_mfma_f32_16x16x32_bf16(aH, Bl, acc[t], 0, 0, 0);
        }
    }
#pragma unroll
    for (int t = 0; t < 8; ++t) {
#pragma unroll
        for (int rg = 0; rg < 4; ++rg) {
            size_t row = r0 + kg * 4 + rg;
            int col = t * 16 + lrow;
            if (t < 4) tb[row * 64 + col] = f2bf(acc[t][rg]);
            else       ub[row * 64 + (col - 64)] = f2bf(acc[t][rg]);
        }
    }
}

// ------- layer-2 gather (bf16 t, chunk-4) + combine: z = mean(t)+u+b2 ---------
__global__ __launch_bounds__(256) void agg_z_kernel(
    const ushort* __restrict__ tb, const ushort* __restrict__ ub,
    const float* __restrict__ b2, const int* __restrict__ off,
    const int* __restrict__ srcS, ushort* __restrict__ zb) {
    int n = blockIdx.x * 8 + (threadIdx.x >> 5);   // 2 nodes per wave
    if (n >= N_NODES) return;
    int l = threadIdx.x & 31;                      // channels 2l, 2l+1
    int s0 = off[n], s1 = off[n + 1];
    float ax = 0.0f, ay = 0.0f;
    int k = s0;
    for (; k + 4 <= s1; k += 4) {
        int sa = srcS[k], sb = srcS[k + 1], sc = srcS[k + 2], sd = srcS[k + 3];
        uint va = *(const uint*)(tb + (size_t)sa * 64 + l * 2);
        uint vb = *(const uint*)(tb + (size_t)sb * 64 + l * 2);
        uint vc = *(const uint*)(tb + (size_t)sc * 64 + l * 2);
        uint vd = *(const uint*)(tb + (size_t)sd * 64 + l * 2);
        ax += bflo(va) + bflo(vb) + bflo(vc) + bflo(vd);
        ay += bfhi(va) + bfhi(vb) + bfhi(vc) + bfhi(vd);
    }
    for (; k < s1; ++k) {
        uint v = *(const uint*)(tb + (size_t)srcS[k] * 64 + l * 2);
        ax += bflo(v);
        ay += bfhi(v);
    }
    float inv = (s1 > s0) ? 1.0f / (float)(s1 - s0) : 0.0f;
    uint uu = *(const uint*)(ub + (size_t)n * 64 + l * 2);
    float zx = ax * inv + bflo(uu) + b2[l * 2];
    float zy = ay * inv + bfhi(uu) + b2[l * 2 + 1];
    uint pz = (uint)f2bf(zx) | ((uint)f2bf(zy) << 16);
    *(uint*)(zb + (size_t)n * 64 + l * 2) = pz;
}

// ---------------- decode over bf16 z ------------------------------------------
__global__ __launch_bounds__(256) void decode_kernel(
    const ushort* __restrict__ zb,
    const int* __restrict__ pos, const int* __restrict__ neg,
    float* __restrict__ out) {
    int t = blockIdx.x * 256 + threadIdx.x;
    int g = t >> 4;
    int lane = t & 15;
    if (g >= 2 * NEP) return;
    const int* ei;
    int e;
    float* o;
    if (g < NEP) { ei = pos; e = g; o = out; }
    else         { ei = neg; e = g - NEP; o = out + NEP; }
    int a  = ei[e];
    int bn = ei[NEP + e];
    ushort4 va = *reinterpret_cast<const ushort4*>(zb + (size_t)a  * 64 + lane * 4);
    ushort4 vb = *reinterpret_cast<const ushort4*>(zb + (size_t)bn * 64 + lane * 4);
    float s = bf2f(va.x) * bf2f(vb.x) + bf2f(va.y) * bf2f(vb.y)
            + bf2f(va.z) * bf2f(vb.z) + bf2f(va.w) * bf2f(vb.w);
    s += __shfl_xor(s, 1);
    s += __shfl_xor(s, 2);
    s += __shfl_xor(s, 4);
    s += __shfl_xor(s, 8);
    if (lane == 0) o[e] = s;
}

extern "C" void kernel_launch(void* const* d_in, const int* in_sizes, int n_in,
                              void* d_out, int out_size, void* d_ws, size_t ws_size,
                              hipStream_t stream) {
    const float* x    = (const float*)d_in[0];
    const int*   ei   = (const int*)d_in[1];
    const int*   pos  = (const int*)d_in[2];
    const int*   neg  = (const int*)d_in[3];
    const float* Wl1  = (const float*)d_in[4];
    const float* Wr1  = (const float*)d_in[5];
    const float* b1   = (const float*)d_in[6];
    const float* Wl2  = (const float*)d_in[7];
    const float* Wr2  = (const float*)d_in[8];
    const float* b2   = (const float*)d_in[9];
    float* out = (float*)d_out;

    const size_t HALF = (size_t)N_NODES * 128 * 2;   // 25.6 MB (one bf16 plane)
    char* ws = (char*)d_ws;
    // region1: xb plane | hb plane (both live during gemm1)
    ushort* xb = (ushort*)ws;                        // N*128 bf16
    ushort* hb = (ushort*)(ws + HALF);               // N*128 bf16
    // region2: meanH | meanL planes; after gemm1 reused by tb|ub|zb
    ushort* meanH = (ushort*)(ws + 2 * HALF);        // N*128 bf16
    ushort* meanL = (ushort*)(ws + 3 * HALF);        // N*128 bf16
    ushort* tb = (ushort*)(ws + 2 * HALF);                               // N*64 bf16
    ushort* ub = (ushort*)(ws + 2 * HALF + (size_t)N_NODES * 64 * 2);    // N*64 bf16
    ushort* zb = (ushort*)(ws + 2 * HALF + (size_t)N_NODES * 64 * 4);    // N*64 bf16
    // ints + packed weights
    int* cnt  = (int*)(ws + 4 * HALF);
    int* off  = cnt + N_NODES;
    int* off2 = off + N_NODES + 1;
    int* srcS = off2 + N_NODES;
    int* sums = srcS + NE;
    ushort* b1h = (ushort*)(sums + 512);
    ushort* b1l = b1h + 32768;
    ushort* b2h = b1l + 32768;
    ushort* b2l = b2h + 16384;

    // ---- CSR build ----
    hipMemsetAsync(cnt, 0, N_NODES * sizeof(int), stream);
    hist_kernel <<<(NE + 255) / 256, 256, 0, stream>>>(ei, cnt);
    scan1_kernel<<<NBLK_SCAN, 256, 0, stream>>>(cnt, off, sums);
    scan2_kernel<<<1, 512, 0, stream>>>(sums);
    scan3_kernel<<<NBLK_SCAN, 256, 0, stream>>>(off, off2, sums);
    fill_kernel <<<(NE + 255) / 256, 256, 0, stream>>>(ei, off2, srcS);

    // ---- weight packing + x->bf16 ----
    wconv1_kernel<<<128, 256, 0, stream>>>(Wl1, Wr1, b1h, b1l);
    wconv2_kernel<<<64, 256, 0, stream>>>(Wl2, Wr2, b2h, b2l);
    xconv_kernel<<<12500, 256, 0, stream>>>(x, xb);

    // ---- layer 1 ----
    agg_mean_kernel<<<N_NODES / 4, 256, 0, stream>>>(xb, off, srcS, meanH, meanL);
    gemm1_kernel<<<(N_NODES / 16 + 3) / 4, 256, 0, stream>>>(meanH, meanL, xb, b1h, b1l, b1, hb);

    // ---- layer 2 (transform-then-aggregate) ----
    gemm2_kernel<<<(N_NODES / 16 + 3) / 4, 256, 0, stream>>>(hb, b2h, b2l, tb, ub);
    agg_z_kernel<<<(N_NODES + 7) / 8, 256, 0, stream>>>(tb, ub, b2, off, srcS, zb);

    // ---- decode ----
    decode_kernel<<<(2 * NEP * 16) / 256, 256, 0, stream>>>(zb, pos, neg, out);
}